// Round 3
// baseline (2189.125 us; speedup 1.0000x reference)
//
#include <hip/hip_runtime.h>

#define DIN 128
#define DH 64
#define DOUT 128

// ---------------- degree / norm (in-place in dinv buffer) ----------------
__global__ __launch_bounds__(256) void k_deg_init(float* __restrict__ deg, int n) {
  int i = blockIdx.x * 256 + threadIdx.x;
  if (i < n) deg[i] = 1.0f;  // self-loop
}

__global__ __launch_bounds__(256) void k_deg_count(const int* __restrict__ dst,
                                                   float* __restrict__ deg, int E) {
  int e = blockIdx.x * 256 + threadIdx.x;
  if (e < E) atomicAdd(&deg[dst[e]], 1.0f);
}

__global__ __launch_bounds__(256) void k_dinv(float* __restrict__ dinv, int n) {
  int i = blockIdx.x * 256 + threadIdx.x;
  if (i < n) dinv[i] = rsqrtf(dinv[i]);
}

// ---------------- GEMM1: h0 = x @ W1  ([n,128]@[128,64]) ----------------
// 32-row tile, 256 threads, each thread 2 rows x 4 cols. LDS = 48.9 KB.
__global__ __launch_bounds__(256) void k_gemm1(const float* __restrict__ x,
                                               const float* __restrict__ W1,
                                               float* __restrict__ h0, int n) {
  __shared__ float Ws[DIN * DH];       // 32 KB
  __shared__ float xs[32][DIN + 4];    // 16.9 KB, +4 pad kills bank conflicts
  const int t = threadIdx.x;
  for (int i = t; i < DIN * DH; i += 256) Ws[i] = W1[i];
  const int row0 = blockIdx.x * 32;
  for (int i = t; i < 32 * (DIN / 4); i += 256) {
    int r = i >> 5;                 // /32
    int k4 = (i & 31) * 4;
    float4 v = make_float4(0.f, 0.f, 0.f, 0.f);
    int row = row0 + r;
    if (row < n) v = *(const float4*)&x[(long)row * DIN + k4];
    *(float4*)&xs[r][k4] = v;
  }
  __syncthreads();
  const int tc = t & 15, tr = t >> 4;
  const int col4 = tc * 4, r0 = tr * 2;  // 2 rows x 4 cols per thread
  float acc[2][4];
#pragma unroll
  for (int r = 0; r < 2; r++)
#pragma unroll
    for (int c = 0; c < 4; c++) acc[r][c] = 0.f;
  for (int k4 = 0; k4 < DIN; k4 += 4) {
    float4 xv[2];
#pragma unroll
    for (int r = 0; r < 2; r++) xv[r] = *(const float4*)&xs[r0 + r][k4];
#pragma unroll
    for (int kk = 0; kk < 4; kk++) {
      float4 wv = *(const float4*)&Ws[(k4 + kk) * DH + col4];
#pragma unroll
      for (int r = 0; r < 2; r++) {
        float xval = (&xv[r].x)[kk];
        acc[r][0] = fmaf(xval, wv.x, acc[r][0]);
        acc[r][1] = fmaf(xval, wv.y, acc[r][1]);
        acc[r][2] = fmaf(xval, wv.z, acc[r][2]);
        acc[r][3] = fmaf(xval, wv.w, acc[r][3]);
      }
    }
  }
#pragma unroll
  for (int r = 0; r < 2; r++) {
    int row = row0 + r0 + r;
    if (row < n)
      *(float4*)&h0[(long)row * DH + col4] =
          make_float4(acc[r][0], acc[r][1], acc[r][2], acc[r][3]);
  }
}

// ---------------- h1 = b1 + h0 * dinv^2 (self-loop term + bias) ----------------
__global__ __launch_bounds__(256) void k_init_h1(const float* __restrict__ h0,
                                                 const float* __restrict__ b1,
                                                 const float* __restrict__ dinv,
                                                 float* __restrict__ h1, int n) {
  int i = blockIdx.x * 256 + threadIdx.x;  // over n*16 float4 groups
  if (i >= n * (DH / 4)) return;
  int row = i >> 4;
  int f4 = (i & 15) * 4;
  float di = dinv[row];
  float w = di * di;
  float4 h = *(const float4*)&h0[(long)row * DH + f4];
  float4 b = *(const float4*)&b1[f4];
  float4 o;
  o.x = b.x + h.x * w;
  o.y = b.y + h.y * w;
  o.z = b.z + h.z * w;
  o.w = b.w + h.w * w;
  *(float4*)&h1[(long)row * DH + f4] = o;
}

// ---------------- edge scatter: out[dst] += h[src]*norm ----------------
// LOGL: log2(threads per edge); feature dim = (1<<LOGL)*4
template <int LOGL>
__global__ __launch_bounds__(256) void k_scatter(const int* __restrict__ srcp,
                                                 const int* __restrict__ dstp,
                                                 const float* __restrict__ dinv,
                                                 const float* __restrict__ h,
                                                 float* __restrict__ out, int E) {
  const int L = 1 << LOGL;
  const int F = L * 4;
  long gid = (long)blockIdx.x * 256 + threadIdx.x;
  int e = (int)(gid >> LOGL);
  if (e >= E) return;
  int l = (int)(gid & (L - 1));
  int s = srcp[e], d = dstp[e];
  float norm = dinv[s] * dinv[d];
  float4 v = *(const float4*)&h[(long)s * F + l * 4];
  float* o = &out[(long)d * F + l * 4];
  atomicAdd(o + 0, v.x * norm);
  atomicAdd(o + 1, v.y * norm);
  atomicAdd(o + 2, v.z * norm);
  atomicAdd(o + 3, v.w * norm);
}

// ---------------- g = relu(h1) @ W2  ([n,64]@[64,128]) ----------------
// 32-row tile, 256 threads, 4 rows x 4 cols each. relu applied when staging.
__global__ __launch_bounds__(256) void k_gemmA(const float* __restrict__ h1,
                                               const float* __restrict__ W2,
                                               float* __restrict__ g, int n) {
  __shared__ float Ws[DH * DOUT];     // 32 KB
  __shared__ float hs[32][DH + 4];    // 8.7 KB
  const int t = threadIdx.x;
  for (int i = t; i < DH * DOUT; i += 256) Ws[i] = W2[i];
  const int row0 = blockIdx.x * 32;
  for (int i = t; i < 32 * (DH / 4); i += 256) {
    int r = i >> 4;
    int k4 = (i & 15) * 4;
    float4 v = make_float4(0.f, 0.f, 0.f, 0.f);
    int row = row0 + r;
    if (row < n) v = *(const float4*)&h1[(long)row * DH + k4];
    v.x = fmaxf(v.x, 0.f); v.y = fmaxf(v.y, 0.f);
    v.z = fmaxf(v.z, 0.f); v.w = fmaxf(v.w, 0.f);
    *(float4*)&hs[r][k4] = v;
  }
  __syncthreads();
  const int tc = t & 31, tr = t >> 5;
  const int col4 = tc * 4, r0 = tr * 4;
  float acc[4][4];
#pragma unroll
  for (int r = 0; r < 4; r++)
#pragma unroll
    for (int c = 0; c < 4; c++) acc[r][c] = 0.f;
  for (int k4 = 0; k4 < DH; k4 += 4) {
    float4 hv[4];
#pragma unroll
    for (int r = 0; r < 4; r++) hv[r] = *(const float4*)&hs[r0 + r][k4];
#pragma unroll
    for (int kk = 0; kk < 4; kk++) {
      float4 wv = *(const float4*)&Ws[(k4 + kk) * DOUT + col4];
#pragma unroll
      for (int r = 0; r < 4; r++) {
        float hval = (&hv[r].x)[kk];
        acc[r][0] = fmaf(hval, wv.x, acc[r][0]);
        acc[r][1] = fmaf(hval, wv.y, acc[r][1]);
        acc[r][2] = fmaf(hval, wv.z, acc[r][2]);
        acc[r][3] = fmaf(hval, wv.w, acc[r][3]);
      }
    }
  }
#pragma unroll
  for (int r = 0; r < 4; r++) {
    int row = row0 + r0 + r;
    if (row < n)
      *(float4*)&g[(long)row * DOUT + col4] =
          make_float4(acc[r][0], acc[r][1], acc[r][2], acc[r][3]);
  }
}

// ---------------- out = x + h1@Wl + bl + b2 + g*dinv^2 ----------------
__global__ __launch_bounds__(256) void k_gemmB(const float* __restrict__ h1,
                                               const float* __restrict__ Wl,
                                               const float* __restrict__ bl,
                                               const float* __restrict__ b2,
                                               const float* __restrict__ x,
                                               const float* __restrict__ dinv,
                                               const float* __restrict__ g,
                                               float* __restrict__ out, int n) {
  __shared__ float Ws[DH * DOUT];     // 32 KB
  __shared__ float hs[32][DH + 4];
  const int t = threadIdx.x;
  for (int i = t; i < DH * DOUT; i += 256) Ws[i] = Wl[i];
  const int row0 = blockIdx.x * 32;
  for (int i = t; i < 32 * (DH / 4); i += 256) {
    int r = i >> 4;
    int k4 = (i & 15) * 4;
    float4 v = make_float4(0.f, 0.f, 0.f, 0.f);
    int row = row0 + r;
    if (row < n) v = *(const float4*)&h1[(long)row * DH + k4];
    *(float4*)&hs[r][k4] = v;
  }
  __syncthreads();
  const int tc = t & 31, tr = t >> 5;
  const int col4 = tc * 4, r0 = tr * 4;
  float acc[4][4];
#pragma unroll
  for (int r = 0; r < 4; r++)
#pragma unroll
    for (int c = 0; c < 4; c++) acc[r][c] = 0.f;
  for (int k4 = 0; k4 < DH; k4 += 4) {
    float4 hv[4];
#pragma unroll
    for (int r = 0; r < 4; r++) hv[r] = *(const float4*)&hs[r0 + r][k4];
#pragma unroll
    for (int kk = 0; kk < 4; kk++) {
      float4 wv = *(const float4*)&Ws[(k4 + kk) * DOUT + col4];
#pragma unroll
      for (int r = 0; r < 4; r++) {
        float hval = (&hv[r].x)[kk];
        acc[r][0] = fmaf(hval, wv.x, acc[r][0]);
        acc[r][1] = fmaf(hval, wv.y, acc[r][1]);
        acc[r][2] = fmaf(hval, wv.z, acc[r][2]);
        acc[r][3] = fmaf(hval, wv.w, acc[r][3]);
      }
    }
  }
  float4 blv = *(const float4*)&bl[col4];
  float4 b2v = *(const float4*)&b2[col4];
#pragma unroll
  for (int r = 0; r < 4; r++) {
    int row = row0 + r0 + r;
    if (row < n) {
      float di = dinv[row];
      float w = di * di;
      float4 xv = *(const float4*)&x[(long)row * DOUT + col4];
      float4 gv = *(const float4*)&g[(long)row * DOUT + col4];
      float4 o;
      o.x = xv.x + acc[r][0] + blv.x + b2v.x + gv.x * w;
      o.y = xv.y + acc[r][1] + blv.y + b2v.y + gv.y * w;
      o.z = xv.z + acc[r][2] + blv.z + b2v.z + gv.z * w;
      o.w = xv.w + acc[r][3] + blv.w + b2v.w + gv.w * w;
      *(float4*)&out[(long)row * DOUT + col4] = o;
    }
  }
}

extern "C" void kernel_launch(void* const* d_in, const int* in_sizes, int n_in,
                              void* d_out, int out_size, void* d_ws, size_t ws_size,
                              hipStream_t stream) {
  const float* x = (const float*)d_in[0];
  const int* edge_index = (const int*)d_in[1];   // harness stages integers as int32
  const float* W1 = (const float*)d_in[2];
  const float* b1 = (const float*)d_in[3];
  const float* Wl = (const float*)d_in[4];
  const float* bl = (const float*)d_in[5];
  const float* W2 = (const float*)d_in[6];
  const float* b2 = (const float*)d_in[7];
  float* out = (float*)d_out;

  const int n = in_sizes[0] / DIN;   // 50000
  const int E = in_sizes[1] / 2;     // 800000
  const int* src = edge_index;
  const int* dst = edge_index + E;

  // workspace carve (floats), total n*193 = 38.6 MB:
  //   [dinv: n][h1: n*64][g: n*128]   with h0 overlaid on g's first n*64
  //   (h0 is dead before g is written by k_gemmA)
  float* dinv = (float*)d_ws;
  float* h1 = dinv + n;
  float* g = h1 + (size_t)n * DH;
  float* h0 = g;  // overlay: h0 uses g's first n*64 floats

  const int B = 256;
  k_deg_init<<<(n + B - 1) / B, B, 0, stream>>>(dinv, n);
  k_deg_count<<<(E + B - 1) / B, B, 0, stream>>>(dst, dinv, E);
  k_dinv<<<(n + B - 1) / B, B, 0, stream>>>(dinv, n);

  k_gemm1<<<(n + 31) / 32, B, 0, stream>>>(x, W1, h0, n);
  k_init_h1<<<(n * (DH / 4) + B - 1) / B, B, 0, stream>>>(h0, b1, dinv, h1, n);
  // conv1 edge scatter: 16 lanes/edge (64 feats / 4)
  {
    long total = (long)E * 16;
    k_scatter<4><<<(unsigned)((total + B - 1) / B), B, 0, stream>>>(src, dst, dinv, h0, h1, E);
  }

  k_gemmA<<<(n + 31) / 32, B, 0, stream>>>(h1, W2, g, n);
  k_gemmB<<<(n + 31) / 32, B, 0, stream>>>(h1, Wl, bl, b2, x, dinv, g, out, n);
  // conv2 edge scatter: 32 lanes/edge (128 feats / 4)
  {
    long total = (long)E * 32;
    k_scatter<5><<<(unsigned)((total + B - 1) / B), B, 0, stream>>>(src, dst, dinv, g, out, E);
  }
}

// Round 4
// 445.391 us; speedup vs baseline: 4.9151x; 4.9151x over previous
//
#include <hip/hip_runtime.h>

#define DIN 128
#define DH 64
#define DOUT 128

// ---------------- degree histogram (int) ----------------
__global__ __launch_bounds__(256) void k_zero_int(int* __restrict__ p, int n) {
  int i = blockIdx.x * 256 + threadIdx.x;
  if (i < n) p[i] = 0;
}

__global__ __launch_bounds__(256) void k_count(const int* __restrict__ dst,
                                               int* __restrict__ deg, int E) {
  int e = blockIdx.x * 256 + threadIdx.x;
  if (e < E) atomicAdd(&deg[dst[e]], 1);
}

__global__ __launch_bounds__(256) void k_dinv(const int* __restrict__ deg,
                                              float* __restrict__ dinv, int n) {
  int i = blockIdx.x * 256 + threadIdx.x;
  if (i < n) dinv[i] = rsqrtf(1.0f + (float)deg[i]);  // +1 self-loop
}

// ---------------- single-block exclusive scan over n degrees ----------------
// Writes offsets[0..n] and rewrites deg_cursor[i] = offsets[i] (fill cursor).
__global__ __launch_bounds__(1024) void k_scan(int* __restrict__ deg_cursor,
                                               int* __restrict__ offsets, int n, int E) {
  __shared__ int sums[1024];
  const int t = threadIdx.x;
  const int chunk = (n + 1023) / 1024;
  const int a = t * chunk;
  const int b = min(a + chunk, n);
  int s = 0;
  for (int i = a; i < b; i++) s += deg_cursor[i];
  sums[t] = s;
  __syncthreads();
  for (int off = 1; off < 1024; off <<= 1) {
    int v = 0;
    if (t >= off) v = sums[t - off];
    __syncthreads();
    if (t >= off) sums[t] += v;
    __syncthreads();
  }
  int run = (t == 0) ? 0 : sums[t - 1];
  for (int i = a; i < b; i++) {
    int d = deg_cursor[i];
    offsets[i] = run;
    deg_cursor[i] = run;  // cursor for fill
    run += d;
  }
  if (t == 0) offsets[n] = E;
}

// ---------------- CSR fill: bucket src by dst ----------------
__global__ __launch_bounds__(256) void k_fill(const int* __restrict__ src,
                                              const int* __restrict__ dst,
                                              int* __restrict__ cursor,
                                              int* __restrict__ csr_src, int E) {
  int e = blockIdx.x * 256 + threadIdx.x;
  if (e < E) {
    int pos = atomicAdd(&cursor[dst[e]], 1);
    csr_src[pos] = src[e];
  }
}

// ---------------- GEMM1: h0 = x @ W1  ([n,128]@[128,64]) ----------------
__global__ __launch_bounds__(256) void k_gemm1(const float* __restrict__ x,
                                               const float* __restrict__ W1,
                                               float* __restrict__ h0, int n) {
  __shared__ float Ws[DIN * DH];       // 32 KB
  __shared__ float xs[32][DIN + 4];    // 16.9 KB
  const int t = threadIdx.x;
  for (int i = t; i < DIN * DH; i += 256) Ws[i] = W1[i];
  const int row0 = blockIdx.x * 32;
  for (int i = t; i < 32 * (DIN / 4); i += 256) {
    int r = i >> 5;
    int k4 = (i & 31) * 4;
    float4 v = make_float4(0.f, 0.f, 0.f, 0.f);
    int row = row0 + r;
    if (row < n) v = *(const float4*)&x[(long)row * DIN + k4];
    *(float4*)&xs[r][k4] = v;
  }
  __syncthreads();
  const int tc = t & 15, tr = t >> 4;
  const int col4 = tc * 4, r0 = tr * 2;
  float acc[2][4];
#pragma unroll
  for (int r = 0; r < 2; r++)
#pragma unroll
    for (int c = 0; c < 4; c++) acc[r][c] = 0.f;
  for (int k4 = 0; k4 < DIN; k4 += 4) {
    float4 xv[2];
#pragma unroll
    for (int r = 0; r < 2; r++) xv[r] = *(const float4*)&xs[r0 + r][k4];
#pragma unroll
    for (int kk = 0; kk < 4; kk++) {
      float4 wv = *(const float4*)&Ws[(k4 + kk) * DH + col4];
#pragma unroll
      for (int r = 0; r < 2; r++) {
        float xval = (&xv[r].x)[kk];
        acc[r][0] = fmaf(xval, wv.x, acc[r][0]);
        acc[r][1] = fmaf(xval, wv.y, acc[r][1]);
        acc[r][2] = fmaf(xval, wv.z, acc[r][2]);
        acc[r][3] = fmaf(xval, wv.w, acc[r][3]);
      }
    }
  }
#pragma unroll
  for (int r = 0; r < 2; r++) {
    int row = row0 + r0 + r;
    if (row < n)
      *(float4*)&h0[(long)row * DH + col4] =
          make_float4(acc[r][0], acc[r][1], acc[r][2], acc[r][3]);
  }
}

// ---------------- conv1 gather: h1 = b1 + h0*dinv^2 + sum_{e} h0[src]*norm ----------------
// 16 lanes per node (64 feats / 4).
__global__ __launch_bounds__(256) void k_gather1(const int* __restrict__ offs,
                                                 const int* __restrict__ csr,
                                                 const float* __restrict__ dinv,
                                                 const float* __restrict__ h0,
                                                 const float* __restrict__ b1,
                                                 float* __restrict__ h1, int n) {
  long gid = (long)blockIdx.x * 256 + threadIdx.x;
  int node = (int)(gid >> 4);
  if (node >= n) return;
  int l = (int)(gid & 15);
  const float dd = dinv[node];
  const int beg = offs[node], end = offs[node + 1];
  float4 acc = make_float4(0.f, 0.f, 0.f, 0.f);
  int j = beg;
  for (; j + 1 < end; j += 2) {
    int s0 = csr[j], s1 = csr[j + 1];
    float w0 = dinv[s0] * dd, w1 = dinv[s1] * dd;
    float4 v0 = *(const float4*)&h0[(long)s0 * DH + l * 4];
    float4 v1 = *(const float4*)&h0[(long)s1 * DH + l * 4];
    acc.x = fmaf(v0.x, w0, acc.x); acc.y = fmaf(v0.y, w0, acc.y);
    acc.z = fmaf(v0.z, w0, acc.z); acc.w = fmaf(v0.w, w0, acc.w);
    acc.x = fmaf(v1.x, w1, acc.x); acc.y = fmaf(v1.y, w1, acc.y);
    acc.z = fmaf(v1.z, w1, acc.z); acc.w = fmaf(v1.w, w1, acc.w);
  }
  if (j < end) {
    int s0 = csr[j];
    float w0 = dinv[s0] * dd;
    float4 v0 = *(const float4*)&h0[(long)s0 * DH + l * 4];
    acc.x = fmaf(v0.x, w0, acc.x); acc.y = fmaf(v0.y, w0, acc.y);
    acc.z = fmaf(v0.z, w0, acc.z); acc.w = fmaf(v0.w, w0, acc.w);
  }
  const float w = dd * dd;
  float4 self = *(const float4*)&h0[(long)node * DH + l * 4];
  float4 b = *(const float4*)&b1[l * 4];
  float4 o;
  o.x = b.x + self.x * w + acc.x;
  o.y = b.y + self.y * w + acc.y;
  o.z = b.z + self.z * w + acc.z;
  o.w = b.w + self.w * w + acc.w;
  *(float4*)&h1[(long)node * DH + l * 4] = o;
}

// ---------------- conv2 gather: out += sum_{e} g[src]*norm (plain RMW) ----------------
// 32 lanes per node (128 feats / 4). Self term already in out via k_gemmB.
__global__ __launch_bounds__(256) void k_gather2(const int* __restrict__ offs,
                                                 const int* __restrict__ csr,
                                                 const float* __restrict__ dinv,
                                                 const float* __restrict__ g,
                                                 float* __restrict__ out, int n) {
  long gid = (long)blockIdx.x * 256 + threadIdx.x;
  int node = (int)(gid >> 5);
  if (node >= n) return;
  int l = (int)(gid & 31);
  const float dd = dinv[node];
  const int beg = offs[node], end = offs[node + 1];
  float4 acc = make_float4(0.f, 0.f, 0.f, 0.f);
  int j = beg;
  for (; j + 1 < end; j += 2) {
    int s0 = csr[j], s1 = csr[j + 1];
    float w0 = dinv[s0] * dd, w1 = dinv[s1] * dd;
    float4 v0 = *(const float4*)&g[(long)s0 * DOUT + l * 4];
    float4 v1 = *(const float4*)&g[(long)s1 * DOUT + l * 4];
    acc.x = fmaf(v0.x, w0, acc.x); acc.y = fmaf(v0.y, w0, acc.y);
    acc.z = fmaf(v0.z, w0, acc.z); acc.w = fmaf(v0.w, w0, acc.w);
    acc.x = fmaf(v1.x, w1, acc.x); acc.y = fmaf(v1.y, w1, acc.y);
    acc.z = fmaf(v1.z, w1, acc.z); acc.w = fmaf(v1.w, w1, acc.w);
  }
  if (j < end) {
    int s0 = csr[j];
    float w0 = dinv[s0] * dd;
    float4 v0 = *(const float4*)&g[(long)s0 * DOUT + l * 4];
    acc.x = fmaf(v0.x, w0, acc.x); acc.y = fmaf(v0.y, w0, acc.y);
    acc.z = fmaf(v0.z, w0, acc.z); acc.w = fmaf(v0.w, w0, acc.w);
  }
  float* op = &out[(long)node * DOUT + l * 4];
  float4 o = *(const float4*)op;
  o.x += acc.x; o.y += acc.y; o.z += acc.z; o.w += acc.w;
  *(float4*)op = o;
}

// ---------------- g = relu(h1) @ W2  ([n,64]@[64,128]) ----------------
__global__ __launch_bounds__(256) void k_gemmA(const float* __restrict__ h1,
                                               const float* __restrict__ W2,
                                               float* __restrict__ g, int n) {
  __shared__ float Ws[DH * DOUT];     // 32 KB
  __shared__ float hs[32][DH + 4];    // 8.7 KB
  const int t = threadIdx.x;
  for (int i = t; i < DH * DOUT; i += 256) Ws[i] = W2[i];
  const int row0 = blockIdx.x * 32;
  for (int i = t; i < 32 * (DH / 4); i += 256) {
    int r = i >> 4;
    int k4 = (i & 15) * 4;
    float4 v = make_float4(0.f, 0.f, 0.f, 0.f);
    int row = row0 + r;
    if (row < n) v = *(const float4*)&h1[(long)row * DH + k4];
    v.x = fmaxf(v.x, 0.f); v.y = fmaxf(v.y, 0.f);
    v.z = fmaxf(v.z, 0.f); v.w = fmaxf(v.w, 0.f);
    *(float4*)&hs[r][k4] = v;
  }
  __syncthreads();
  const int tc = t & 31, tr = t >> 5;
  const int col4 = tc * 4, r0 = tr * 4;
  float acc[4][4];
#pragma unroll
  for (int r = 0; r < 4; r++)
#pragma unroll
    for (int c = 0; c < 4; c++) acc[r][c] = 0.f;
  for (int k4 = 0; k4 < DH; k4 += 4) {
    float4 hv[4];
#pragma unroll
    for (int r = 0; r < 4; r++) hv[r] = *(const float4*)&hs[r0 + r][k4];
#pragma unroll
    for (int kk = 0; kk < 4; kk++) {
      float4 wv = *(const float4*)&Ws[(k4 + kk) * DOUT + col4];
#pragma unroll
      for (int r = 0; r < 4; r++) {
        float hval = (&hv[r].x)[kk];
        acc[r][0] = fmaf(hval, wv.x, acc[r][0]);
        acc[r][1] = fmaf(hval, wv.y, acc[r][1]);
        acc[r][2] = fmaf(hval, wv.z, acc[r][2]);
        acc[r][3] = fmaf(hval, wv.w, acc[r][3]);
      }
    }
  }
#pragma unroll
  for (int r = 0; r < 4; r++) {
    int row = row0 + r0 + r;
    if (row < n)
      *(float4*)&g[(long)row * DOUT + col4] =
          make_float4(acc[r][0], acc[r][1], acc[r][2], acc[r][3]);
  }
}

// ---------------- out = x + h1@Wl + bl + b2 + g*dinv^2 ----------------
__global__ __launch_bounds__(256) void k_gemmB(const float* __restrict__ h1,
                                               const float* __restrict__ Wl,
                                               const float* __restrict__ bl,
                                               const float* __restrict__ b2,
                                               const float* __restrict__ x,
                                               const float* __restrict__ dinv,
                                               const float* __restrict__ g,
                                               float* __restrict__ out, int n) {
  __shared__ float Ws[DH * DOUT];
  __shared__ float hs[32][DH + 4];
  const int t = threadIdx.x;
  for (int i = t; i < DH * DOUT; i += 256) Ws[i] = Wl[i];
  const int row0 = blockIdx.x * 32;
  for (int i = t; i < 32 * (DH / 4); i += 256) {
    int r = i >> 4;
    int k4 = (i & 15) * 4;
    float4 v = make_float4(0.f, 0.f, 0.f, 0.f);
    int row = row0 + r;
    if (row < n) v = *(const float4*)&h1[(long)row * DH + k4];
    *(float4*)&hs[r][k4] = v;
  }
  __syncthreads();
  const int tc = t & 31, tr = t >> 5;
  const int col4 = tc * 4, r0 = tr * 4;
  float acc[4][4];
#pragma unroll
  for (int r = 0; r < 4; r++)
#pragma unroll
    for (int c = 0; c < 4; c++) acc[r][c] = 0.f;
  for (int k4 = 0; k4 < DH; k4 += 4) {
    float4 hv[4];
#pragma unroll
    for (int r = 0; r < 4; r++) hv[r] = *(const float4*)&hs[r0 + r][k4];
#pragma unroll
    for (int kk = 0; kk < 4; kk++) {
      float4 wv = *(const float4*)&Ws[(k4 + kk) * DOUT + col4];
#pragma unroll
      for (int r = 0; r < 4; r++) {
        float hval = (&hv[r].x)[kk];
        acc[r][0] = fmaf(hval, wv.x, acc[r][0]);
        acc[r][1] = fmaf(hval, wv.y, acc[r][1]);
        acc[r][2] = fmaf(hval, wv.z, acc[r][2]);
        acc[r][3] = fmaf(hval, wv.w, acc[r][3]);
      }
    }
  }
  float4 blv = *(const float4*)&bl[col4];
  float4 b2v = *(const float4*)&b2[col4];
#pragma unroll
  for (int r = 0; r < 4; r++) {
    int row = row0 + r0 + r;
    if (row < n) {
      float di = dinv[row];
      float w = di * di;
      float4 xv = *(const float4*)&x[(long)row * DOUT + col4];
      float4 gv = *(const float4*)&g[(long)row * DOUT + col4];
      float4 o;
      o.x = xv.x + acc[r][0] + blv.x + b2v.x + gv.x * w;
      o.y = xv.y + acc[r][1] + blv.y + b2v.y + gv.y * w;
      o.z = xv.z + acc[r][2] + blv.z + b2v.z + gv.z * w;
      o.w = xv.w + acc[r][3] + blv.w + b2v.w + gv.w * w;
      *(float4*)&out[(long)row * DOUT + col4] = o;
    }
  }
}

extern "C" void kernel_launch(void* const* d_in, const int* in_sizes, int n_in,
                              void* d_out, int out_size, void* d_ws, size_t ws_size,
                              hipStream_t stream) {
  const float* x = (const float*)d_in[0];
  const int* edge_index = (const int*)d_in[1];   // harness stages integers as int32
  const float* W1 = (const float*)d_in[2];
  const float* b1 = (const float*)d_in[3];
  const float* Wl = (const float*)d_in[4];
  const float* bl = (const float*)d_in[5];
  const float* W2 = (const float*)d_in[6];
  const float* b2 = (const float*)d_in[7];
  float* out = (float*)d_out;

  const int n = in_sizes[0] / DIN;   // 50000
  const int E = in_sizes[1] / 2;     // 800000
  const int* src = edge_index;
  const int* dst = edge_index + E;

  // workspace carve (~42.6 MB):
  //   dinv[n] f32 | deg_cursor[n] i32 | offsets[n+4] i32 | csr_src[E] i32
  //   | h1[n*64] f32 | g[n*128] f32  (h0 overlaid on g's first n*64)
  float* dinv = (float*)d_ws;
  int* deg = (int*)(dinv + n);
  int* offs = deg + n;
  int* csr = offs + ((n + 4) & ~3);
  float* h1 = (float*)(csr + E);
  float* g = h1 + (size_t)n * DH;
  float* h0 = g;  // overlay: h0 dead before g written

  const int B = 256;
  // ---- CSR build ----
  k_zero_int<<<(n + B - 1) / B, B, 0, stream>>>(deg, n);
  k_count<<<(E + B - 1) / B, B, 0, stream>>>(dst, deg, E);
  k_dinv<<<(n + B - 1) / B, B, 0, stream>>>(deg, dinv, n);
  k_scan<<<1, 1024, 0, stream>>>(deg, offs, n, E);
  k_fill<<<(E + B - 1) / B, B, 0, stream>>>(src, dst, deg, csr, E);

  // ---- layer 1 ----
  k_gemm1<<<(n + 31) / 32, B, 0, stream>>>(x, W1, h0, n);
  k_gather1<<<(int)(((long)n * 16 + B - 1) / B), B, 0, stream>>>(offs, csr, dinv, h0, b1, h1, n);

  // ---- layer 2 + residuals ----
  k_gemmA<<<(n + 31) / 32, B, 0, stream>>>(h1, W2, g, n);
  k_gemmB<<<(n + 31) / 32, B, 0, stream>>>(h1, Wl, bl, b2, x, dinv, g, out, n);
  k_gather2<<<(int)(((long)n * 32 + B - 1) / B), B, 0, stream>>>(offs, csr, dinv, g, out, n);
}

// Round 5
// 346.542 us; speedup vs baseline: 6.3171x; 1.2852x over previous
//
#include <hip/hip_runtime.h>

#define DIN 128
#define DH 64
#define DOUT 128

// ---------------- degree histogram (int) ----------------
__global__ __launch_bounds__(256) void k_zero_int(int* __restrict__ p, int n) {
  int i = blockIdx.x * 256 + threadIdx.x;
  if (i < n) p[i] = 0;
}

__global__ __launch_bounds__(256) void k_count(const int* __restrict__ dst,
                                               int* __restrict__ deg, int E) {
  int e = blockIdx.x * 256 + threadIdx.x;
  if (e < E) atomicAdd(&deg[dst[e]], 1);
}

// ---------------- hierarchical exclusive scan (n <= 256*256) ----------------
// scan1: per-block exclusive scan of deg -> offs, block totals -> bsum.
//        Also computes dinv = rsqrt(1+deg) (fused; deg needed here anyway).
__global__ __launch_bounds__(256) void k_scan1(const int* __restrict__ deg,
                                               int* __restrict__ offs,
                                               int* __restrict__ bsum,
                                               float* __restrict__ dinv, int n) {
  const int t = threadIdx.x;
  int i = blockIdx.x * 256 + t;
  int d = (i < n) ? deg[i] : 0;
  if (i < n) dinv[i] = rsqrtf(1.0f + (float)d);
  __shared__ int s[256];
  s[t] = d;
  __syncthreads();
#pragma unroll
  for (int off = 1; off < 256; off <<= 1) {
    int v = (t >= off) ? s[t - off] : 0;
    __syncthreads();
    s[t] += v;
    __syncthreads();
  }
  if (i < n) offs[i] = s[t] - d;  // exclusive
  if (t == 255) bsum[blockIdx.x] = s[255];
}

// scan2: single block scans the block sums (nb <= 256).
__global__ __launch_bounds__(256) void k_scan2(int* __restrict__ bsum, int nb) {
  const int t = threadIdx.x;
  int v = (t < nb) ? bsum[t] : 0;
  __shared__ int s[256];
  s[t] = v;
  __syncthreads();
#pragma unroll
  for (int off = 1; off < 256; off <<= 1) {
    int u = (t >= off) ? s[t - off] : 0;
    __syncthreads();
    s[t] += u;
    __syncthreads();
  }
  if (t < nb) bsum[t] = s[t] - v;  // exclusive
}

// scan3: add block offsets back; materialize fill cursor; offs[n] = E.
__global__ __launch_bounds__(256) void k_scan3(int* __restrict__ offs,
                                               const int* __restrict__ bsum,
                                               int* __restrict__ cursor, int n, int E) {
  int i = blockIdx.x * 256 + threadIdx.x;
  if (i < n) {
    int o = offs[i] + bsum[blockIdx.x];
    offs[i] = o;
    cursor[i] = o;
  }
  if (i == 0) offs[n] = E;
}

// ---------------- CSR fill: bucket src by dst ----------------
__global__ __launch_bounds__(256) void k_fill(const int* __restrict__ src,
                                              const int* __restrict__ dst,
                                              int* __restrict__ cursor,
                                              int* __restrict__ csr_src, int E) {
  int e = blockIdx.x * 256 + threadIdx.x;
  if (e < E) {
    int pos = atomicAdd(&cursor[dst[e]], 1);
    csr_src[pos] = src[e];
  }
}

// ---------------- GEMM1: h0 = x @ W1  ([n,128]@[128,64]) ----------------
__global__ __launch_bounds__(256) void k_gemm1(const float* __restrict__ x,
                                               const float* __restrict__ W1,
                                               float* __restrict__ h0, int n) {
  __shared__ float Ws[DIN * DH];       // 32 KB
  __shared__ float xs[32][DIN + 4];    // 16.9 KB
  const int t = threadIdx.x;
  for (int i = t; i < DIN * DH; i += 256) Ws[i] = W1[i];
  const int row0 = blockIdx.x * 32;
  for (int i = t; i < 32 * (DIN / 4); i += 256) {
    int r = i >> 5;
    int k4 = (i & 31) * 4;
    float4 v = make_float4(0.f, 0.f, 0.f, 0.f);
    int row = row0 + r;
    if (row < n) v = *(const float4*)&x[(long)row * DIN + k4];
    *(float4*)&xs[r][k4] = v;
  }
  __syncthreads();
  const int tc = t & 15, tr = t >> 4;
  const int col4 = tc * 4, r0 = tr * 2;
  float acc[2][4];
#pragma unroll
  for (int r = 0; r < 2; r++)
#pragma unroll
    for (int c = 0; c < 4; c++) acc[r][c] = 0.f;
  for (int k4 = 0; k4 < DIN; k4 += 4) {
    float4 xv[2];
#pragma unroll
    for (int r = 0; r < 2; r++) xv[r] = *(const float4*)&xs[r0 + r][k4];
#pragma unroll
    for (int kk = 0; kk < 4; kk++) {
      float4 wv = *(const float4*)&Ws[(k4 + kk) * DH + col4];
#pragma unroll
      for (int r = 0; r < 2; r++) {
        float xval = (&xv[r].x)[kk];
        acc[r][0] = fmaf(xval, wv.x, acc[r][0]);
        acc[r][1] = fmaf(xval, wv.y, acc[r][1]);
        acc[r][2] = fmaf(xval, wv.z, acc[r][2]);
        acc[r][3] = fmaf(xval, wv.w, acc[r][3]);
      }
    }
  }
#pragma unroll
  for (int r = 0; r < 2; r++) {
    int row = row0 + r0 + r;
    if (row < n)
      *(float4*)&h0[(long)row * DH + col4] =
          make_float4(acc[r][0], acc[r][1], acc[r][2], acc[r][3]);
  }
}

// ---------------- conv1 gather: h1 = b1 + h0*dinv^2 + sum_{e} h0[src]*norm ----------------
// 16 lanes per node (64 feats / 4).
__global__ __launch_bounds__(256) void k_gather1(const int* __restrict__ offs,
                                                 const int* __restrict__ csr,
                                                 const float* __restrict__ dinv,
                                                 const float* __restrict__ h0,
                                                 const float* __restrict__ b1,
                                                 float* __restrict__ h1, int n) {
  long gid = (long)blockIdx.x * 256 + threadIdx.x;
  int node = (int)(gid >> 4);
  if (node >= n) return;
  int l = (int)(gid & 15);
  const float dd = dinv[node];
  const int beg = offs[node], end = offs[node + 1];
  float4 acc = make_float4(0.f, 0.f, 0.f, 0.f);
  int j = beg;
  for (; j + 1 < end; j += 2) {
    int s0 = csr[j], s1 = csr[j + 1];
    float w0 = dinv[s0] * dd, w1 = dinv[s1] * dd;
    float4 v0 = *(const float4*)&h0[(long)s0 * DH + l * 4];
    float4 v1 = *(const float4*)&h0[(long)s1 * DH + l * 4];
    acc.x = fmaf(v0.x, w0, acc.x); acc.y = fmaf(v0.y, w0, acc.y);
    acc.z = fmaf(v0.z, w0, acc.z); acc.w = fmaf(v0.w, w0, acc.w);
    acc.x = fmaf(v1.x, w1, acc.x); acc.y = fmaf(v1.y, w1, acc.y);
    acc.z = fmaf(v1.z, w1, acc.z); acc.w = fmaf(v1.w, w1, acc.w);
  }
  if (j < end) {
    int s0 = csr[j];
    float w0 = dinv[s0] * dd;
    float4 v0 = *(const float4*)&h0[(long)s0 * DH + l * 4];
    acc.x = fmaf(v0.x, w0, acc.x); acc.y = fmaf(v0.y, w0, acc.y);
    acc.z = fmaf(v0.z, w0, acc.z); acc.w = fmaf(v0.w, w0, acc.w);
  }
  const float w = dd * dd;
  float4 self = *(const float4*)&h0[(long)node * DH + l * 4];
  float4 b = *(const float4*)&b1[l * 4];
  float4 o;
  o.x = b.x + self.x * w + acc.x;
  o.y = b.y + self.y * w + acc.y;
  o.z = b.z + self.z * w + acc.z;
  o.w = b.w + self.w * w + acc.w;
  *(float4*)&h1[(long)node * DH + l * 4] = o;
}

// ---------------- conv2 gather: out += sum_{e} g[src]*norm (plain RMW) ----------------
// 32 lanes per node (128 feats / 4). Self term already in out via k_gemmB.
__global__ __launch_bounds__(256) void k_gather2(const int* __restrict__ offs,
                                                 const int* __restrict__ csr,
                                                 const float* __restrict__ dinv,
                                                 const float* __restrict__ g,
                                                 float* __restrict__ out, int n) {
  long gid = (long)blockIdx.x * 256 + threadIdx.x;
  int node = (int)(gid >> 5);
  if (node >= n) return;
  int l = (int)(gid & 31);
  const float dd = dinv[node];
  const int beg = offs[node], end = offs[node + 1];
  float4 acc = make_float4(0.f, 0.f, 0.f, 0.f);
  int j = beg;
  for (; j + 1 < end; j += 2) {
    int s0 = csr[j], s1 = csr[j + 1];
    float w0 = dinv[s0] * dd, w1 = dinv[s1] * dd;
    float4 v0 = *(const float4*)&g[(long)s0 * DOUT + l * 4];
    float4 v1 = *(const float4*)&g[(long)s1 * DOUT + l * 4];
    acc.x = fmaf(v0.x, w0, acc.x); acc.y = fmaf(v0.y, w0, acc.y);
    acc.z = fmaf(v0.z, w0, acc.z); acc.w = fmaf(v0.w, w0, acc.w);
    acc.x = fmaf(v1.x, w1, acc.x); acc.y = fmaf(v1.y, w1, acc.y);
    acc.z = fmaf(v1.z, w1, acc.z); acc.w = fmaf(v1.w, w1, acc.w);
  }
  if (j < end) {
    int s0 = csr[j];
    float w0 = dinv[s0] * dd;
    float4 v0 = *(const float4*)&g[(long)s0 * DOUT + l * 4];
    acc.x = fmaf(v0.x, w0, acc.x); acc.y = fmaf(v0.y, w0, acc.y);
    acc.z = fmaf(v0.z, w0, acc.z); acc.w = fmaf(v0.w, w0, acc.w);
  }
  float* op = &out[(long)node * DOUT + l * 4];
  float4 o = *(const float4*)op;
  o.x += acc.x; o.y += acc.y; o.z += acc.z; o.w += acc.w;
  *(float4*)op = o;
}

// ---------------- g = relu(h1) @ W2  ([n,64]@[64,128]) ----------------
__global__ __launch_bounds__(256) void k_gemmA(const float* __restrict__ h1,
                                               const float* __restrict__ W2,
                                               float* __restrict__ g, int n) {
  __shared__ float Ws[DH * DOUT];     // 32 KB
  __shared__ float hs[32][DH + 4];    // 8.7 KB
  const int t = threadIdx.x;
  for (int i = t; i < DH * DOUT; i += 256) Ws[i] = W2[i];
  const int row0 = blockIdx.x * 32;
  for (int i = t; i < 32 * (DH / 4); i += 256) {
    int r = i >> 4;
    int k4 = (i & 15) * 4;
    float4 v = make_float4(0.f, 0.f, 0.f, 0.f);
    int row = row0 + r;
    if (row < n) v = *(const float4*)&h1[(long)row * DH + k4];
    v.x = fmaxf(v.x, 0.f); v.y = fmaxf(v.y, 0.f);
    v.z = fmaxf(v.z, 0.f); v.w = fmaxf(v.w, 0.f);
    *(float4*)&hs[r][k4] = v;
  }
  __syncthreads();
  const int tc = t & 31, tr = t >> 5;
  const int col4 = tc * 4, r0 = tr * 4;
  float acc[4][4];
#pragma unroll
  for (int r = 0; r < 4; r++)
#pragma unroll
    for (int c = 0; c < 4; c++) acc[r][c] = 0.f;
  for (int k4 = 0; k4 < DH; k4 += 4) {
    float4 hv[4];
#pragma unroll
    for (int r = 0; r < 4; r++) hv[r] = *(const float4*)&hs[r0 + r][k4];
#pragma unroll
    for (int kk = 0; kk < 4; kk++) {
      float4 wv = *(const float4*)&Ws[(k4 + kk) * DOUT + col4];
#pragma unroll
      for (int r = 0; r < 4; r++) {
        float hval = (&hv[r].x)[kk];
        acc[r][0] = fmaf(hval, wv.x, acc[r][0]);
        acc[r][1] = fmaf(hval, wv.y, acc[r][1]);
        acc[r][2] = fmaf(hval, wv.z, acc[r][2]);
        acc[r][3] = fmaf(hval, wv.w, acc[r][3]);
      }
    }
  }
#pragma unroll
  for (int r = 0; r < 4; r++) {
    int row = row0 + r0 + r;
    if (row < n)
      *(float4*)&g[(long)row * DOUT + col4] =
          make_float4(acc[r][0], acc[r][1], acc[r][2], acc[r][3]);
  }
}

// ---------------- out = x + h1@Wl + bl + b2 + g*dinv^2 ----------------
__global__ __launch_bounds__(256) void k_gemmB(const float* __restrict__ h1,
                                               const float* __restrict__ Wl,
                                               const float* __restrict__ bl,
                                               const float* __restrict__ b2,
                                               const float* __restrict__ x,
                                               const float* __restrict__ dinv,
                                               const float* __restrict__ g,
                                               float* __restrict__ out, int n) {
  __shared__ float Ws[DH * DOUT];
  __shared__ float hs[32][DH + 4];
  const int t = threadIdx.x;
  for (int i = t; i < DH * DOUT; i += 256) Ws[i] = Wl[i];
  const int row0 = blockIdx.x * 32;
  for (int i = t; i < 32 * (DH / 4); i += 256) {
    int r = i >> 4;
    int k4 = (i & 15) * 4;
    float4 v = make_float4(0.f, 0.f, 0.f, 0.f);
    int row = row0 + r;
    if (row < n) v = *(const float4*)&h1[(long)row * DH + k4];
    *(float4*)&hs[r][k4] = v;
  }
  __syncthreads();
  const int tc = t & 31, tr = t >> 5;
  const int col4 = tc * 4, r0 = tr * 4;
  float acc[4][4];
#pragma unroll
  for (int r = 0; r < 4; r++)
#pragma unroll
    for (int c = 0; c < 4; c++) acc[r][c] = 0.f;
  for (int k4 = 0; k4 < DH; k4 += 4) {
    float4 hv[4];
#pragma unroll
    for (int r = 0; r < 4; r++) hv[r] = *(const float4*)&hs[r0 + r][k4];
#pragma unroll
    for (int kk = 0; kk < 4; kk++) {
      float4 wv = *(const float4*)&Ws[(k4 + kk) * DOUT + col4];
#pragma unroll
      for (int r = 0; r < 4; r++) {
        float hval = (&hv[r].x)[kk];
        acc[r][0] = fmaf(hval, wv.x, acc[r][0]);
        acc[r][1] = fmaf(hval, wv.y, acc[r][1]);
        acc[r][2] = fmaf(hval, wv.z, acc[r][2]);
        acc[r][3] = fmaf(hval, wv.w, acc[r][3]);
      }
    }
  }
  float4 blv = *(const float4*)&bl[col4];
  float4 b2v = *(const float4*)&b2[col4];
#pragma unroll
  for (int r = 0; r < 4; r++) {
    int row = row0 + r0 + r;
    if (row < n) {
      float di = dinv[row];
      float w = di * di;
      float4 xv = *(const float4*)&x[(long)row * DOUT + col4];
      float4 gv = *(const float4*)&g[(long)row * DOUT + col4];
      float4 o;
      o.x = xv.x + acc[r][0] + blv.x + b2v.x + gv.x * w;
      o.y = xv.y + acc[r][1] + blv.y + b2v.y + gv.y * w;
      o.z = xv.z + acc[r][2] + blv.z + b2v.z + gv.z * w;
      o.w = xv.w + acc[r][3] + blv.w + b2v.w + gv.w * w;
      *(float4*)&out[(long)row * DOUT + col4] = o;
    }
  }
}

extern "C" void kernel_launch(void* const* d_in, const int* in_sizes, int n_in,
                              void* d_out, int out_size, void* d_ws, size_t ws_size,
                              hipStream_t stream) {
  const float* x = (const float*)d_in[0];
  const int* edge_index = (const int*)d_in[1];   // harness stages integers as int32
  const float* W1 = (const float*)d_in[2];
  const float* b1 = (const float*)d_in[3];
  const float* Wl = (const float*)d_in[4];
  const float* bl = (const float*)d_in[5];
  const float* W2 = (const float*)d_in[6];
  const float* b2 = (const float*)d_in[7];
  float* out = (float*)d_out;

  const int n = in_sizes[0] / DIN;   // 50000
  const int E = in_sizes[1] / 2;     // 800000
  const int* src = edge_index;
  const int* dst = edge_index + E;
  const int NB = (n + 255) / 256;    // 196 scan blocks (<= 256)

  // workspace carve (~42.6 MB):
  //   dinv[n] f32 | deg/cursor[n] i32 | offsets[n+4] i32 | bsum[256] i32
  //   | csr_src[E] i32 | h1[n*64] f32 | g[n*128] f32 (h0 overlaid on g)
  float* dinv = (float*)d_ws;
  int* deg = (int*)(dinv + n);
  int* offs = deg + n;
  int* bsum = offs + ((n + 4) & ~3);
  int* csr = bsum + 256;
  float* h1 = (float*)(csr + E);
  float* g = h1 + (size_t)n * DH;
  float* h0 = g;  // overlay: h0 dead before g written

  const int B = 256;
  // ---- CSR build ----
  k_zero_int<<<(n + B - 1) / B, B, 0, stream>>>(deg, n);
  k_count<<<(E + B - 1) / B, B, 0, stream>>>(dst, deg, E);
  k_scan1<<<NB, B, 0, stream>>>(deg, offs, bsum, dinv, n);
  k_scan2<<<1, B, 0, stream>>>(bsum, NB);
  k_scan3<<<NB, B, 0, stream>>>(offs, bsum, deg, n, E);  // cursor -> deg
  k_fill<<<(E + B - 1) / B, B, 0, stream>>>(src, dst, deg, csr, E);

  // ---- layer 1 ----
  k_gemm1<<<(n + 31) / 32, B, 0, stream>>>(x, W1, h0, n);
  k_gather1<<<(int)(((long)n * 16 + B - 1) / B), B, 0, stream>>>(offs, csr, dinv, h0, b1, h1, n);

  // ---- layer 2 + residuals ----
  k_gemmA<<<(n + 31) / 32, B, 0, stream>>>(h1, W2, g, n);
  k_gemmB<<<(n + 31) / 32, B, 0, stream>>>(h1, Wl, bl, b2, x, dinv, g, out, n);
  k_gather2<<<(int)(((long)n * 32 + B - 1) / B), B, 0, stream>>>(offs, csr, dinv, g, out, n);
}

// Round 6
// 302.056 us; speedup vs baseline: 7.2474x; 1.1473x over previous
//
#include <hip/hip_runtime.h>

#define DIN 128
#define DH 64
#define DOUT 128

// ---------------- degree histogram (int) ----------------
__global__ __launch_bounds__(256) void k_count(const int* __restrict__ dst,
                                               int* __restrict__ deg, int E) {
  int e = blockIdx.x * 256 + threadIdx.x;
  if (e < E) atomicAdd(&deg[dst[e]], 1);
}

// ---------------- hierarchical exclusive scan (n <= 256*256) ----------------
__global__ __launch_bounds__(256) void k_scan1(const int* __restrict__ deg,
                                               int* __restrict__ offs,
                                               int* __restrict__ bsum,
                                               float* __restrict__ dinv, int n) {
  const int t = threadIdx.x;
  int i = blockIdx.x * 256 + t;
  int d = (i < n) ? deg[i] : 0;
  if (i < n) dinv[i] = rsqrtf(1.0f + (float)d);
  __shared__ int s[256];
  s[t] = d;
  __syncthreads();
#pragma unroll
  for (int off = 1; off < 256; off <<= 1) {
    int v = (t >= off) ? s[t - off] : 0;
    __syncthreads();
    s[t] += v;
    __syncthreads();
  }
  if (i < n) offs[i] = s[t] - d;  // exclusive
  if (t == 255) bsum[blockIdx.x] = s[255];
}

__global__ __launch_bounds__(256) void k_scan2(int* __restrict__ bsum, int nb) {
  const int t = threadIdx.x;
  int v = (t < nb) ? bsum[t] : 0;
  __shared__ int s[256];
  s[t] = v;
  __syncthreads();
#pragma unroll
  for (int off = 1; off < 256; off <<= 1) {
    int u = (t >= off) ? s[t - off] : 0;
    __syncthreads();
    s[t] += u;
    __syncthreads();
  }
  if (t < nb) bsum[t] = s[t] - v;  // exclusive
}

__global__ __launch_bounds__(256) void k_scan3(int* __restrict__ offs,
                                               const int* __restrict__ bsum,
                                               int* __restrict__ cursor, int n, int E) {
  int i = blockIdx.x * 256 + threadIdx.x;
  if (i < n) {
    int o = offs[i] + bsum[blockIdx.x];
    offs[i] = o;
    cursor[i] = o;
  }
  if (i == 0) offs[n] = E;
}

// ---------------- CSR fill: bucket src by dst ----------------
__global__ __launch_bounds__(256) void k_fill(const int* __restrict__ src,
                                              const int* __restrict__ dst,
                                              int* __restrict__ cursor,
                                              int* __restrict__ csr_src, int E) {
  int e = blockIdx.x * 256 + threadIdx.x;
  if (e < E) {
    int pos = atomicAdd(&cursor[dst[e]], 1);
    csr_src[pos] = src[e];
  }
}

// ---------------- GEMM1: h0 = x @ W1  ([n,128]@[128,64]) ----------------
__global__ __launch_bounds__(256) void k_gemm1(const float* __restrict__ x,
                                               const float* __restrict__ W1,
                                               float* __restrict__ h0, int n) {
  __shared__ float Ws[DIN * DH];       // 32 KB
  __shared__ float xs[32][DIN + 4];    // 16.9 KB
  const int t = threadIdx.x;
  for (int i = t; i < DIN * DH; i += 256) Ws[i] = W1[i];
  const int row0 = blockIdx.x * 32;
  for (int i = t; i < 32 * (DIN / 4); i += 256) {
    int r = i >> 5;
    int k4 = (i & 31) * 4;
    float4 v = make_float4(0.f, 0.f, 0.f, 0.f);
    int row = row0 + r;
    if (row < n) v = *(const float4*)&x[(long)row * DIN + k4];
    *(float4*)&xs[r][k4] = v;
  }
  __syncthreads();
  const int tc = t & 15, tr = t >> 4;
  const int col4 = tc * 4, r0 = tr * 2;
  float acc[2][4];
#pragma unroll
  for (int r = 0; r < 2; r++)
#pragma unroll
    for (int c = 0; c < 4; c++) acc[r][c] = 0.f;
  for (int k4 = 0; k4 < DIN; k4 += 4) {
    float4 xv[2];
#pragma unroll
    for (int r = 0; r < 2; r++) xv[r] = *(const float4*)&xs[r0 + r][k4];
#pragma unroll
    for (int kk = 0; kk < 4; kk++) {
      float4 wv = *(const float4*)&Ws[(k4 + kk) * DH + col4];
#pragma unroll
      for (int r = 0; r < 2; r++) {
        float xval = (&xv[r].x)[kk];
        acc[r][0] = fmaf(xval, wv.x, acc[r][0]);
        acc[r][1] = fmaf(xval, wv.y, acc[r][1]);
        acc[r][2] = fmaf(xval, wv.z, acc[r][2]);
        acc[r][3] = fmaf(xval, wv.w, acc[r][3]);
      }
    }
  }
#pragma unroll
  for (int r = 0; r < 2; r++) {
    int row = row0 + r0 + r;
    if (row < n)
      *(float4*)&h0[(long)row * DH + col4] =
          make_float4(acc[r][0], acc[r][1], acc[r][2], acc[r][3]);
  }
}

// ---------------- conv1 gather: h1 = b1 + h0*dinv^2 + sum_{e} h0[src]*norm ----------------
// 16 lanes per node (64 feats / 4).
__global__ __launch_bounds__(256) void k_gather1(const int* __restrict__ offs,
                                                 const int* __restrict__ csr,
                                                 const float* __restrict__ dinv,
                                                 const float* __restrict__ h0,
                                                 const float* __restrict__ b1,
                                                 float* __restrict__ h1, int n) {
  long gid = (long)blockIdx.x * 256 + threadIdx.x;
  int node = (int)(gid >> 4);
  if (node >= n) return;
  int l = (int)(gid & 15);
  const float dd = dinv[node];
  const int beg = offs[node], end = offs[node + 1];
  float4 acc = make_float4(0.f, 0.f, 0.f, 0.f);
  int j = beg;
  for (; j + 1 < end; j += 2) {
    int s0 = csr[j], s1 = csr[j + 1];
    float w0 = dinv[s0] * dd, w1 = dinv[s1] * dd;
    float4 v0 = *(const float4*)&h0[(long)s0 * DH + l * 4];
    float4 v1 = *(const float4*)&h0[(long)s1 * DH + l * 4];
    acc.x = fmaf(v0.x, w0, acc.x); acc.y = fmaf(v0.y, w0, acc.y);
    acc.z = fmaf(v0.z, w0, acc.z); acc.w = fmaf(v0.w, w0, acc.w);
    acc.x = fmaf(v1.x, w1, acc.x); acc.y = fmaf(v1.y, w1, acc.y);
    acc.z = fmaf(v1.z, w1, acc.z); acc.w = fmaf(v1.w, w1, acc.w);
  }
  if (j < end) {
    int s0 = csr[j];
    float w0 = dinv[s0] * dd;
    float4 v0 = *(const float4*)&h0[(long)s0 * DH + l * 4];
    acc.x = fmaf(v0.x, w0, acc.x); acc.y = fmaf(v0.y, w0, acc.y);
    acc.z = fmaf(v0.z, w0, acc.z); acc.w = fmaf(v0.w, w0, acc.w);
  }
  const float w = dd * dd;
  float4 self = *(const float4*)&h0[(long)node * DH + l * 4];
  float4 b = *(const float4*)&b1[l * 4];
  float4 o;
  o.x = b.x + self.x * w + acc.x;
  o.y = b.y + self.y * w + acc.y;
  o.z = b.z + self.z * w + acc.z;
  o.w = b.w + self.w * w + acc.w;
  *(float4*)&h1[(long)node * DH + l * 4] = o;
}

// ---------------- conv2 gather (pre-W2): z = relu(h1[node])*dinv^2 + sum relu(h1[src])*norm ----
// Algebra: (sum norm*relu(h1)[src]) @ W2 == sum norm*(relu(h1)[src] @ W2).
// Gathering the 64-wide relu(h1) instead of the 128-wide g halves traffic.
__global__ __launch_bounds__(256) void k_gather2(const int* __restrict__ offs,
                                                 const int* __restrict__ csr,
                                                 const float* __restrict__ dinv,
                                                 const float* __restrict__ h1,
                                                 float* __restrict__ z, int n) {
  long gid = (long)blockIdx.x * 256 + threadIdx.x;
  int node = (int)(gid >> 4);
  if (node >= n) return;
  int l = (int)(gid & 15);
  const float dd = dinv[node];
  const int beg = offs[node], end = offs[node + 1];
  float4 acc = make_float4(0.f, 0.f, 0.f, 0.f);
  int j = beg;
  for (; j + 1 < end; j += 2) {
    int s0 = csr[j], s1 = csr[j + 1];
    float w0 = dinv[s0] * dd, w1 = dinv[s1] * dd;
    float4 v0 = *(const float4*)&h1[(long)s0 * DH + l * 4];
    float4 v1 = *(const float4*)&h1[(long)s1 * DH + l * 4];
    v0.x = fmaxf(v0.x, 0.f); v0.y = fmaxf(v0.y, 0.f);
    v0.z = fmaxf(v0.z, 0.f); v0.w = fmaxf(v0.w, 0.f);
    v1.x = fmaxf(v1.x, 0.f); v1.y = fmaxf(v1.y, 0.f);
    v1.z = fmaxf(v1.z, 0.f); v1.w = fmaxf(v1.w, 0.f);
    acc.x = fmaf(v0.x, w0, acc.x); acc.y = fmaf(v0.y, w0, acc.y);
    acc.z = fmaf(v0.z, w0, acc.z); acc.w = fmaf(v0.w, w0, acc.w);
    acc.x = fmaf(v1.x, w1, acc.x); acc.y = fmaf(v1.y, w1, acc.y);
    acc.z = fmaf(v1.z, w1, acc.z); acc.w = fmaf(v1.w, w1, acc.w);
  }
  if (j < end) {
    int s0 = csr[j];
    float w0 = dinv[s0] * dd;
    float4 v0 = *(const float4*)&h1[(long)s0 * DH + l * 4];
    v0.x = fmaxf(v0.x, 0.f); v0.y = fmaxf(v0.y, 0.f);
    v0.z = fmaxf(v0.z, 0.f); v0.w = fmaxf(v0.w, 0.f);
    acc.x = fmaf(v0.x, w0, acc.x); acc.y = fmaf(v0.y, w0, acc.y);
    acc.z = fmaf(v0.z, w0, acc.z); acc.w = fmaf(v0.w, w0, acc.w);
  }
  const float w = dd * dd;
  float4 self = *(const float4*)&h1[(long)node * DH + l * 4];
  self.x = fmaxf(self.x, 0.f); self.y = fmaxf(self.y, 0.f);
  self.z = fmaxf(self.z, 0.f); self.w = fmaxf(self.w, 0.f);
  float4 o;
  o.x = self.x * w + acc.x;
  o.y = self.y * w + acc.y;
  o.z = self.z * w + acc.z;
  o.w = self.w * w + acc.w;
  *(float4*)&z[(long)node * DH + l * 4] = o;
}

// ---------------- out = x + h1@Wl + z@W2 + (bl+b2) ----------------
// Two-phase: phase 0 accumulates h1@Wl, phase 1 accumulates z@W2 (LDS reused).
__global__ __launch_bounds__(256) void k_gemmC(const float* __restrict__ h1,
                                               const float* __restrict__ z,
                                               const float* __restrict__ Wl,
                                               const float* __restrict__ W2,
                                               const float* __restrict__ bl,
                                               const float* __restrict__ b2,
                                               const float* __restrict__ x,
                                               float* __restrict__ out, int n) {
  __shared__ float Ws[DH * DOUT];     // 32 KB
  __shared__ float hs[32][DH + 4];    // 8.7 KB
  const int t = threadIdx.x;
  const int row0 = blockIdx.x * 32;
  const int tc = t & 31, tr = t >> 5;
  const int col4 = tc * 4, r0 = tr * 4;
  float acc[4][4];
#pragma unroll
  for (int r = 0; r < 4; r++)
#pragma unroll
    for (int c = 0; c < 4; c++) acc[r][c] = 0.f;

#pragma unroll
  for (int phase = 0; phase < 2; phase++) {
    const float* W = phase ? W2 : Wl;
    const float* H = phase ? z : h1;
    for (int i = t; i < DH * DOUT; i += 256) Ws[i] = W[i];
    for (int i = t; i < 32 * (DH / 4); i += 256) {
      int r = i >> 4;
      int k4 = (i & 15) * 4;
      float4 v = make_float4(0.f, 0.f, 0.f, 0.f);
      int row = row0 + r;
      if (row < n) v = *(const float4*)&H[(long)row * DH + k4];
      *(float4*)&hs[r][k4] = v;
    }
    __syncthreads();
    for (int k4 = 0; k4 < DH; k4 += 4) {
      float4 hv[4];
#pragma unroll
      for (int r = 0; r < 4; r++) hv[r] = *(const float4*)&hs[r0 + r][k4];
#pragma unroll
      for (int kk = 0; kk < 4; kk++) {
        float4 wv = *(const float4*)&Ws[(k4 + kk) * DOUT + col4];
#pragma unroll
        for (int r = 0; r < 4; r++) {
          float hval = (&hv[r].x)[kk];
          acc[r][0] = fmaf(hval, wv.x, acc[r][0]);
          acc[r][1] = fmaf(hval, wv.y, acc[r][1]);
          acc[r][2] = fmaf(hval, wv.z, acc[r][2]);
          acc[r][3] = fmaf(hval, wv.w, acc[r][3]);
        }
      }
    }
    __syncthreads();  // before next phase overwrites LDS
  }

  float4 blv = *(const float4*)&bl[col4];
  float4 b2v = *(const float4*)&b2[col4];
#pragma unroll
  for (int r = 0; r < 4; r++) {
    int row = row0 + r0 + r;
    if (row < n) {
      float4 xv = *(const float4*)&x[(long)row * DOUT + col4];
      float4 o;
      o.x = xv.x + acc[r][0] + blv.x + b2v.x;
      o.y = xv.y + acc[r][1] + blv.y + b2v.y;
      o.z = xv.z + acc[r][2] + blv.z + b2v.z;
      o.w = xv.w + acc[r][3] + blv.w + b2v.w;
      *(float4*)&out[(long)row * DOUT + col4] = o;
    }
  }
}

extern "C" void kernel_launch(void* const* d_in, const int* in_sizes, int n_in,
                              void* d_out, int out_size, void* d_ws, size_t ws_size,
                              hipStream_t stream) {
  const float* x = (const float*)d_in[0];
  const int* edge_index = (const int*)d_in[1];   // harness stages integers as int32
  const float* W1 = (const float*)d_in[2];
  const float* b1 = (const float*)d_in[3];
  const float* Wl = (const float*)d_in[4];
  const float* bl = (const float*)d_in[5];
  const float* W2 = (const float*)d_in[6];
  const float* b2 = (const float*)d_in[7];
  float* out = (float*)d_out;

  const int n = in_sizes[0] / DIN;   // 50000
  const int E = in_sizes[1] / 2;     // 800000
  const int* src = edge_index;
  const int* dst = edge_index + E;
  const int NB = (n + 255) / 256;    // scan blocks (<= 256)

  // workspace carve (~29.4 MB):
  //   dinv[n] f32 | deg/cursor[n] i32 | offsets[n+4] i32 | bsum[256] i32
  //   | csr_src[E] i32 | h1[n*64] f32 | h0/z[n*64] f32 (z overlays h0)
  float* dinv = (float*)d_ws;
  int* deg = (int*)(dinv + n);
  int* offs = deg + n;
  int* bsum = offs + ((n + 4) & ~3);
  int* csr = bsum + 256;
  float* h1 = (float*)(csr + E);
  float* h0 = h1 + (size_t)n * DH;
  float* z = h0;  // overlay: h0 dead after k_gather1

  const int B = 256;
  // ---- CSR build ----
  hipMemsetAsync(deg, 0, (size_t)n * sizeof(int), stream);
  k_count<<<(E + B - 1) / B, B, 0, stream>>>(dst, deg, E);
  k_scan1<<<NB, B, 0, stream>>>(deg, offs, bsum, dinv, n);
  k_scan2<<<1, B, 0, stream>>>(bsum, NB);
  k_scan3<<<NB, B, 0, stream>>>(offs, bsum, deg, n, E);  // cursor -> deg
  k_fill<<<(E + B - 1) / B, B, 0, stream>>>(src, dst, deg, csr, E);

  // ---- layer 1 ----
  k_gemm1<<<(n + 31) / 32, B, 0, stream>>>(x, W1, h0, n);
  k_gather1<<<(int)(((long)n * 16 + B - 1) / B), B, 0, stream>>>(offs, csr, dinv, h0, b1, h1, n);

  // ---- conv2 aggregation in 64-dim, then fused epilogue GEMM ----
  k_gather2<<<(int)(((long)n * 16 + B - 1) / B), B, 0, stream>>>(offs, csr, dinv, h1, z, n);
  k_gemmC<<<(n + 31) / 32, B, 0, stream>>>(h1, z, Wl, W2, bl, b2, x, out, n);
}